// Round 9
// baseline (187.606 us; speedup 1.0000x reference)
//
#include <hip/hip_runtime.h>

#define ROWS 8192
#define KDIM 4096
#define NDIM 4096
#define KSEG 4
#define SEGK 1024

typedef float f32x4 __attribute__((ext_vector_type(4)));

// ws layout (floats):
//   w01  : [4096][16]     at 0        (65536)   -- k-major, r2 contiguous
//   w23  : [16][4096]     at 65536    (65536)
//   tpart: [4][8192][16]  at 131072   (524288)
//
// INSTRUMENTATION ROUND: exact R5 kernels (80.3 us verified); tt_tw23 is
// launched 5x (identical writes, benign) so tw23_dur = (total - 80.3)/4.

__device__ inline f32x4 fma4(float s, f32x4 w, f32x4 a) {
    a.x = fmaf(s, w.x, a.x);
    a.y = fmaf(s, w.y, a.y);
    a.z = fmaf(s, w.z, a.z);
    a.w = fmaf(s, w.w, a.w);
    return a;
}
__device__ inline f32x4 shfl_xor4(f32x4 v, int m) {
    v.x = __shfl_xor(v.x, m, 64);
    v.y = __shfl_xor(v.y, m, 64);
    v.z = __shfl_xor(v.z, m, 64);
    v.w = __shfl_xor(v.w, m, 64);
    return v;
}

// ---------------------------------------------------------------------------
// Build W01 (4096x16, k-major) and W23 (16x4096) from the TT cores.
// ---------------------------------------------------------------------------
__global__ __launch_bounds__(256) void tt_prep(
    const float* __restrict__ c0, const float* __restrict__ c1,
    const float* __restrict__ c2, const float* __restrict__ c3,
    float* __restrict__ w01, float* __restrict__ w23)
{
    int gid = blockIdx.x * 256 + threadIdx.x;  // 0..131071
    if (gid < 65536) {
        int p = gid >> 4, r2 = gid & 15;
        int n0 = p >> 6, n1 = p & 63;
        float s = 0.f;
        #pragma unroll
        for (int r1 = 0; r1 < 16; ++r1)
            s = fmaf(c0[n0 * 16 + r1], c1[(r1 * 64 + n1) * 16 + r2], s);
        w01[gid] = s;
    } else {
        int g = gid - 65536;
        int r2 = g >> 12, j = g & 4095;
        int n2 = j >> 6, n3 = j & 63;
        float s = 0.f;
        #pragma unroll
        for (int r3 = 0; r3 < 16; ++r3)
            s = fmaf(c2[(r2 * 64 + n2) * 16 + r3], c3[r3 * 64 + n3], s);
        w23[g] = s;
    }
}

// ---------------------------------------------------------------------------
// T = x @ W01 -> tpart[seg][row][16].  R5-verified broadcast form.
// ---------------------------------------------------------------------------
__global__ __launch_bounds__(256) void tt_xw01(
    const float* __restrict__ x, const float* __restrict__ w01,
    float* __restrict__ tpart)
{
    const int t = threadIdx.x;
    const int lane = t & 63;
    const int wv = t >> 6;
    const int q = lane & 3;
    const int klane = lane >> 2;
    const int row0 = blockIdx.x * 32 + wv * 8;
    const int seg = blockIdx.y;
    const int k0 = seg * SEGK;

    const float* xb = x + (size_t)row0 * KDIM + k0;
    const float* wb = w01 + (size_t)k0 * 16;

    f32x4 acc[8];
    #pragma unroll
    for (int r = 0; r < 8; ++r) acc[r] = (f32x4)(0.f);

    #pragma unroll 2
    for (int it = 0; it < SEGK / 64; ++it) {
        const int kk0 = it * 64 + klane * 4;
        f32x4 wq[4];
        #pragma unroll
        for (int kk = 0; kk < 4; ++kk)
            wq[kk] = *(const f32x4*)&wb[(size_t)(kk0 + kk) * 16 + q * 4];
        f32x4 xv[8];
        #pragma unroll
        for (int r = 0; r < 8; ++r)
            xv[r] = __builtin_nontemporal_load(
                (const f32x4*)&xb[(size_t)r * KDIM + kk0]);
        #pragma unroll
        for (int kk = 0; kk < 4; ++kk)
            #pragma unroll
            for (int r = 0; r < 8; ++r)
                acc[r] = fma4(xv[r][kk], wq[kk], acc[r]);
    }

    const bool b5 = lane & 32, b4 = lane & 16, b3 = lane & 8;
    f32x4 s1[4];
    #pragma unroll
    for (int j = 0; j < 4; ++j) {
        f32x4 send = b5 ? acc[j] : acc[4 + j];
        f32x4 keep = b5 ? acc[4 + j] : acc[j];
        s1[j] = keep + shfl_xor4(send, 32);
    }
    f32x4 s2[2];
    #pragma unroll
    for (int j = 0; j < 2; ++j) {
        f32x4 send = b4 ? s1[j] : s1[2 + j];
        f32x4 keep = b4 ? s1[2 + j] : s1[j];
        s2[j] = keep + shfl_xor4(send, 16);
    }
    f32x4 s3;
    {
        f32x4 send = b3 ? s2[0] : s2[1];
        f32x4 keep = b3 ? s2[1] : s2[0];
        s3 = keep + shfl_xor4(send, 8);
    }
    s3 += shfl_xor4(s3, 4);

    if ((lane & 4) == 0) {
        int row = (lane >> 3) & 7;
        float* tp = tpart + ((size_t)seg * ROWS + row0 + row) * 16 + q * 4;
        *(f32x4*)tp = s3;
    }
}

// ---------------------------------------------------------------------------
// out = T @ W23.  R5-verified: 16 rows x 1024 cols, grid (512,4).
// ---------------------------------------------------------------------------
__global__ __launch_bounds__(256) void tt_tw23(
    const float* __restrict__ tpart, const float* __restrict__ w23,
    float* __restrict__ out)
{
    __shared__ float ts[16][16];
    int rb = blockIdx.x;
    int jb = blockIdx.y;
    int t = threadIdx.x;
    int i0 = rb * 16;
    {
        int row = t >> 4, r = t & 15;
        float s = 0.f;
        #pragma unroll
        for (int seg = 0; seg < KSEG; ++seg)
            s += tpart[((size_t)seg * ROWS + i0 + row) * 16 + r];
        ts[row][r] = s;
    }
    __syncthreads();

    int j0 = jb * 1024 + t * 4;
    f32x4 w[16];
    #pragma unroll
    for (int r = 0; r < 16; ++r)
        w[r] = *(const f32x4*)&w23[r * 4096 + j0];

    #pragma unroll 2
    for (int row = 0; row < 16; ++row) {
        const f32x4* trp = (const f32x4*)&ts[row][0];
        f32x4 t0 = trp[0], t1 = trp[1], t2 = trp[2], t3 = trp[3];
        f32x4 a = (f32x4)(0.f);
        a = fma4(t0.x, w[0],  a); a = fma4(t0.y, w[1],  a);
        a = fma4(t0.z, w[2],  a); a = fma4(t0.w, w[3],  a);
        a = fma4(t1.x, w[4],  a); a = fma4(t1.y, w[5],  a);
        a = fma4(t1.z, w[6],  a); a = fma4(t1.w, w[7],  a);
        a = fma4(t2.x, w[8],  a); a = fma4(t2.y, w[9],  a);
        a = fma4(t2.z, w[10], a); a = fma4(t2.w, w[11], a);
        a = fma4(t3.x, w[12], a); a = fma4(t3.y, w[13], a);
        a = fma4(t3.z, w[14], a); a = fma4(t3.w, w[15], a);
        __builtin_nontemporal_store(a, (f32x4*)&out[(size_t)(i0 + row) * 4096 + j0]);
    }
}

extern "C" void kernel_launch(void* const* d_in, const int* in_sizes, int n_in,
                              void* d_out, int out_size, void* d_ws, size_t ws_size,
                              hipStream_t stream) {
    const float* x  = (const float*)d_in[0];
    const float* c0 = (const float*)d_in[1];
    const float* c1 = (const float*)d_in[2];
    const float* c2 = (const float*)d_in[3];
    const float* c3 = (const float*)d_in[4];
    float* out = (float*)d_out;

    float* w01   = (float*)d_ws;
    float* w23   = w01 + 65536;
    float* tpart = w23 + 65536;

    tt_prep<<<512, 256, 0, stream>>>(c0, c1, c2, c3, w01, w23);
    tt_xw01<<<dim3(256, KSEG), 256, 0, stream>>>(x, w01, tpart);
    // INSTRUMENTATION: 5x identical tw23 launches. Same-stream => serialized;
    // identical values to identical addresses => output unchanged.
    // tw23_dur = (total_dur - 80.3us) / 4.
    for (int rep = 0; rep < 5; ++rep)
        tt_tw23<<<dim3(512, 4), 256, 0, stream>>>(tpart, w23, out);
}

// Round 10
// 119.188 us; speedup vs baseline: 1.5740x; 1.5740x over previous
//
#include <hip/hip_runtime.h>

#define ROWS 8192
#define KDIM 4096
#define NDIM 4096
#define KSEG 4
#define SEGK 1024

typedef float f32x4 __attribute__((ext_vector_type(4)));

// ws layout (floats):
//   w01  : [4096][16]     at 0        (65536)   -- k-major, r2 contiguous
//   w23  : [16][4096]     at 65536    (65536)
//   tpart: [4][8192][16]  at 131072   (524288)

__device__ inline f32x4 fma4(float s, f32x4 w, f32x4 a) {
    a.x = fmaf(s, w.x, a.x);
    a.y = fmaf(s, w.y, a.y);
    a.z = fmaf(s, w.z, a.z);
    a.w = fmaf(s, w.w, a.w);
    return a;
}
__device__ inline f32x4 shfl_xor4(f32x4 v, int m) {
    v.x = __shfl_xor(v.x, m, 64);
    v.y = __shfl_xor(v.y, m, 64);
    v.z = __shfl_xor(v.z, m, 64);
    v.w = __shfl_xor(v.w, m, 64);
    return v;
}

// ---------------------------------------------------------------------------
// Build W01 (4096x16, k-major) and W23 (16x4096) from the TT cores.
// ---------------------------------------------------------------------------
__global__ __launch_bounds__(256) void tt_prep(
    const float* __restrict__ c0, const float* __restrict__ c1,
    const float* __restrict__ c2, const float* __restrict__ c3,
    float* __restrict__ w01, float* __restrict__ w23)
{
    int gid = blockIdx.x * 256 + threadIdx.x;  // 0..131071
    if (gid < 65536) {
        int p = gid >> 4, r2 = gid & 15;
        int n0 = p >> 6, n1 = p & 63;
        float s = 0.f;
        #pragma unroll
        for (int r1 = 0; r1 < 16; ++r1)
            s = fmaf(c0[n0 * 16 + r1], c1[(r1 * 64 + n1) * 16 + r2], s);
        w01[gid] = s;
    } else {
        int g = gid - 65536;
        int r2 = g >> 12, j = g & 4095;
        int n2 = j >> 6, n3 = j & 63;
        float s = 0.f;
        #pragma unroll
        for (int r3 = 0; r3 < 16; ++r3)
            s = fmaf(c2[(r2 * 64 + n2) * 16 + r3], c3[r3 * 64 + n3], s);
        w23[g] = s;
    }
}

// ---------------------------------------------------------------------------
// T = x @ W01 -> tpart[seg][row][16].  Plan G: wave owns r2-quad (wv),
// lane owns k-quad (k = chunk*256 + lane*4) -> every x-load is a fully
// coalesced 1 KB/wave instruction, zero address redundancy. acc[8] = 8 rows
// x wave's 4 r2. All 4 waves read the same 8 rows (L1/L2 absorbs; HBM
// unique traffic unchanged). k-reduction over all 64 lanes: R5-verified
// scatter stages (b5,b4,b3 -> row = lane>>3) + plain m=4,2,1.
// Grid (1024 rowblocks, 4 ksegs) = 4096 blocks; 4 waves/block.
// ---------------------------------------------------------------------------
__global__ __launch_bounds__(256) void tt_xw01(
    const float* __restrict__ x, const float* __restrict__ w01,
    float* __restrict__ tpart)
{
    const int t = threadIdx.x;
    const int lane = t & 63;
    const int wv = t >> 6;            // wave = r2-quad 0..3
    const int row0 = blockIdx.x * 8;
    const int seg = blockIdx.y;
    const int k0 = seg * SEGK;

    const float* xb = x + (size_t)row0 * KDIM + k0;
    const float* wb = w01 + (size_t)k0 * 16 + wv * 4;   // wave's r2-quad col

    f32x4 acc[8];
    #pragma unroll
    for (int r = 0; r < 8; ++r) acc[r] = (f32x4)(0.f);

    #pragma unroll 2
    for (int ch = 0; ch < SEGK / 256; ++ch) {   // 4 chunks of 256 k
        const int kk0 = ch * 256 + lane * 4;    // lane's k-quad
        f32x4 wq[4];
        #pragma unroll
        for (int kk = 0; kk < 4; ++kk)
            wq[kk] = *(const f32x4*)&wb[(size_t)(kk0 + kk) * 16];
        f32x4 xv[8];
        #pragma unroll
        for (int r = 0; r < 8; ++r)
            xv[r] = __builtin_nontemporal_load(
                (const f32x4*)&xb[(size_t)r * KDIM + kk0]);
        #pragma unroll
        for (int kk = 0; kk < 4; ++kk)
            #pragma unroll
            for (int r = 0; r < 8; ++r)
                acc[r] = fma4(xv[r][kk], wq[kk], acc[r]);
    }

    // Reduce over all 64 lanes: scatter bits 5,4,3 (row = lane>>3), then
    // plain butterflies m=4,2,1. Static indices only (rule #20).
    const bool b5 = lane & 32, b4 = lane & 16, b3 = lane & 8;
    f32x4 s1[4];
    #pragma unroll
    for (int j = 0; j < 4; ++j) {
        f32x4 send = b5 ? acc[j] : acc[4 + j];
        f32x4 keep = b5 ? acc[4 + j] : acc[j];
        s1[j] = keep + shfl_xor4(send, 32);
    }
    f32x4 s2[2];
    #pragma unroll
    for (int j = 0; j < 2; ++j) {
        f32x4 send = b4 ? s1[j] : s1[2 + j];
        f32x4 keep = b4 ? s1[2 + j] : s1[j];
        s2[j] = keep + shfl_xor4(send, 16);
    }
    f32x4 s3;
    {
        f32x4 send = b3 ? s2[0] : s2[1];
        f32x4 keep = b3 ? s2[1] : s2[0];
        s3 = keep + shfl_xor4(send, 8);
    }
    s3 += shfl_xor4(s3, 4);
    s3 += shfl_xor4(s3, 2);
    s3 += shfl_xor4(s3, 1);

    if ((lane & 7) == 0) {
        int row = lane >> 3;
        float* tp = tpart + ((size_t)seg * ROWS + row0 + row) * 16 + wv * 4;
        *(f32x4*)tp = s3;
    }
}

// ---------------------------------------------------------------------------
// out = T @ W23.  R5-verified: 16 rows x 1024 cols, grid (512,4).
// ---------------------------------------------------------------------------
__global__ __launch_bounds__(256) void tt_tw23(
    const float* __restrict__ tpart, const float* __restrict__ w23,
    float* __restrict__ out)
{
    __shared__ float ts[16][16];
    int rb = blockIdx.x;
    int jb = blockIdx.y;
    int t = threadIdx.x;
    int i0 = rb * 16;
    {
        int row = t >> 4, r = t & 15;
        float s = 0.f;
        #pragma unroll
        for (int seg = 0; seg < KSEG; ++seg)
            s += tpart[((size_t)seg * ROWS + i0 + row) * 16 + r];
        ts[row][r] = s;
    }
    __syncthreads();

    int j0 = jb * 1024 + t * 4;
    f32x4 w[16];
    #pragma unroll
    for (int r = 0; r < 16; ++r)
        w[r] = *(const f32x4*)&w23[r * 4096 + j0];

    #pragma unroll 2
    for (int row = 0; row < 16; ++row) {
        const f32x4* trp = (const f32x4*)&ts[row][0];
        f32x4 t0 = trp[0], t1 = trp[1], t2 = trp[2], t3 = trp[3];
        f32x4 a = (f32x4)(0.f);
        a = fma4(t0.x, w[0],  a); a = fma4(t0.y, w[1],  a);
        a = fma4(t0.z, w[2],  a); a = fma4(t0.w, w[3],  a);
        a = fma4(t1.x, w[4],  a); a = fma4(t1.y, w[5],  a);
        a = fma4(t1.z, w[6],  a); a = fma4(t1.w, w[7],  a);
        a = fma4(t2.x, w[8],  a); a = fma4(t2.y, w[9],  a);
        a = fma4(t2.z, w[10], a); a = fma4(t2.w, w[11], a);
        a = fma4(t3.x, w[12], a); a = fma4(t3.y, w[13], a);
        a = fma4(t3.z, w[14], a); a = fma4(t3.w, w[15], a);
        __builtin_nontemporal_store(a, (f32x4*)&out[(size_t)(i0 + row) * 4096 + j0]);
    }
}

extern "C" void kernel_launch(void* const* d_in, const int* in_sizes, int n_in,
                              void* d_out, int out_size, void* d_ws, size_t ws_size,
                              hipStream_t stream) {
    const float* x  = (const float*)d_in[0];
    const float* c0 = (const float*)d_in[1];
    const float* c1 = (const float*)d_in[2];
    const float* c2 = (const float*)d_in[3];
    const float* c3 = (const float*)d_in[4];
    float* out = (float*)d_out;

    float* w01   = (float*)d_ws;
    float* w23   = w01 + 65536;
    float* tpart = w23 + 65536;

    tt_prep<<<512, 256, 0, stream>>>(c0, c1, c2, c3, w01, w23);
    tt_xw01<<<dim3(1024, KSEG), 256, 0, stream>>>(x, w01, tpart);
    tt_tw23<<<dim3(512, 4), 256, 0, stream>>>(tpart, w23, out);
}

// Round 11
// 83.718 us; speedup vs baseline: 2.2409x; 1.4237x over previous
//
#include <hip/hip_runtime.h>

#define ROWS 8192
#define KDIM 4096
#define NDIM 4096

typedef float f32x4 __attribute__((ext_vector_type(4)));

// ws layout (floats):
//   w01  : [4096][16]        at 0        (65536)   -- k-major, r2 contiguous
//   w23  : [16][4096]        at 65536    (65536)
//   tpart: [nseg][8192][16]  at 131072   (nseg*131072)

__device__ inline f32x4 fma4(float s, f32x4 w, f32x4 a) {
    a.x = fmaf(s, w.x, a.x);
    a.y = fmaf(s, w.y, a.y);
    a.z = fmaf(s, w.z, a.z);
    a.w = fmaf(s, w.w, a.w);
    return a;
}
__device__ inline f32x4 shfl_xor4(f32x4 v, int m) {
    v.x = __shfl_xor(v.x, m, 64);
    v.y = __shfl_xor(v.y, m, 64);
    v.z = __shfl_xor(v.z, m, 64);
    v.w = __shfl_xor(v.w, m, 64);
    return v;
}

// ---------------------------------------------------------------------------
// Build W01 (4096x16, k-major) and W23 (16x4096) from the TT cores.
// ---------------------------------------------------------------------------
__global__ __launch_bounds__(256) void tt_prep(
    const float* __restrict__ c0, const float* __restrict__ c1,
    const float* __restrict__ c2, const float* __restrict__ c3,
    float* __restrict__ w01, float* __restrict__ w23)
{
    int gid = blockIdx.x * 256 + threadIdx.x;  // 0..131071
    if (gid < 65536) {
        int p = gid >> 4, r2 = gid & 15;
        int n0 = p >> 6, n1 = p & 63;
        float s = 0.f;
        #pragma unroll
        for (int r1 = 0; r1 < 16; ++r1)
            s = fmaf(c0[n0 * 16 + r1], c1[(r1 * 64 + n1) * 16 + r2], s);
        w01[gid] = s;
    } else {
        int g = gid - 65536;
        int r2 = g >> 12, j = g & 4095;
        int n2 = j >> 6, n3 = j & 63;
        float s = 0.f;
        #pragma unroll
        for (int r3 = 0; r3 < 16; ++r3)
            s = fmaf(c2[(r2 * 64 + n2) * 16 + r3], c3[r3 * 64 + n3], s);
        w23[g] = s;
    }
}

// ---------------------------------------------------------------------------
// T = x @ W01 -> tpart[seg][row][16].  Plan H: per-wave LDS staging.
// Stage: wave stages its OWN 8 rows x SEGK floats into private LDS via
//   fully-coalesced 1 KB/instr NT loads (zero redundancy; pure HBM stream).
//   No __syncthreads needed (tile is wave-private; compiler orders ds ops).
// Compute: R5-verified mapping q=lane&3, klane=lane>>2; x comes from LDS
//   where the 4-lane same-address read is a free broadcast (256 B span =
//   2-way bank alias). w01 reads: 16 lines/instr over a 16 KB L1-hot seg.
// Reduction: R5-verified butterfly (scatter b5,b4,b3; plain bit 2).
// Grid (256 rowblocks, NSEG ksegs); 4 waves/block; LDS 4*8*SEGK*4 B.
// ---------------------------------------------------------------------------
template <int SEGK>
__global__ __launch_bounds__(256) void tt_xw01(
    const float* __restrict__ x, const float* __restrict__ w01,
    float* __restrict__ tpart)
{
    __shared__ float ldsx[4][8][SEGK];
    const int t = threadIdx.x;
    const int lane = t & 63;
    const int wv = t >> 6;            // wave 0..3
    const int q = lane & 3;           // r2 quad
    const int klane = lane >> 2;      // 0..15
    const int row0 = blockIdx.x * 32 + wv * 8;
    const int seg = blockIdx.y;
    const int k0 = seg * SEGK;

    const float* xb = x + (size_t)row0 * KDIM + k0;
    const float* wb = w01 + (size_t)k0 * 16;

    // ---- Stage: 8 rows x SEGK floats, coalesced f32x4 (1 KB/wave/instr).
    #pragma unroll
    for (int r = 0; r < 8; ++r) {
        #pragma unroll
        for (int h = 0; h < SEGK / 256; ++h) {
            f32x4 v = __builtin_nontemporal_load(
                (const f32x4*)&xb[(size_t)r * KDIM + h * 256 + lane * 4]);
            *(f32x4*)&ldsx[wv][r][h * 256 + lane * 4] = v;
        }
    }

    // ---- Compute (R5 mapping, x from LDS).
    f32x4 acc[8];
    #pragma unroll
    for (int r = 0; r < 8; ++r) acc[r] = (f32x4)(0.f);

    #pragma unroll 2
    for (int it = 0; it < SEGK / 64; ++it) {
        const int kk0 = it * 64 + klane * 4;
        f32x4 wq[4];
        #pragma unroll
        for (int kk = 0; kk < 4; ++kk)
            wq[kk] = *(const f32x4*)&wb[(size_t)(kk0 + kk) * 16 + q * 4];
        f32x4 xv[8];
        #pragma unroll
        for (int r = 0; r < 8; ++r)
            xv[r] = *(const f32x4*)&ldsx[wv][r][kk0];
        #pragma unroll
        for (int kk = 0; kk < 4; ++kk)
            #pragma unroll
            for (int r = 0; r < 8; ++r)
                acc[r] = fma4(xv[r][kk], wq[kk], acc[r]);
    }

    // ---- Reduce over 16 klanes (R5-verified): scatter bits 5,4,3; plain 2.
    const bool b5 = lane & 32, b4 = lane & 16, b3 = lane & 8;
    f32x4 s1[4];
    #pragma unroll
    for (int j = 0; j < 4; ++j) {
        f32x4 send = b5 ? acc[j] : acc[4 + j];
        f32x4 keep = b5 ? acc[4 + j] : acc[j];
        s1[j] = keep + shfl_xor4(send, 32);
    }
    f32x4 s2[2];
    #pragma unroll
    for (int j = 0; j < 2; ++j) {
        f32x4 send = b4 ? s1[j] : s1[2 + j];
        f32x4 keep = b4 ? s1[2 + j] : s1[j];
        s2[j] = keep + shfl_xor4(send, 16);
    }
    f32x4 s3;
    {
        f32x4 send = b3 ? s2[0] : s2[1];
        f32x4 keep = b3 ? s2[1] : s2[0];
        s3 = keep + shfl_xor4(send, 8);
    }
    s3 += shfl_xor4(s3, 4);           // lane-bit2 pairs identical

    if ((lane & 4) == 0) {
        int row = (lane >> 3) & 7;
        float* tp = tpart + ((size_t)seg * ROWS + row0 + row) * 16 + q * 4;
        *(f32x4*)tp = s3;
    }
}

// ---------------------------------------------------------------------------
// out = T @ W23.  R5-verified form: 16 rows x 1024 cols, grid (512,4);
// runtime nseg for the tpart partial-sum.
// ---------------------------------------------------------------------------
__global__ __launch_bounds__(256) void tt_tw23(
    const float* __restrict__ tpart, const float* __restrict__ w23,
    float* __restrict__ out, int nseg)
{
    __shared__ float ts[16][16];
    int rb = blockIdx.x;
    int jb = blockIdx.y;
    int t = threadIdx.x;
    int i0 = rb * 16;
    {
        int row = t >> 4, r = t & 15;
        float s = 0.f;
        for (int seg = 0; seg < nseg; ++seg)
            s += tpart[((size_t)seg * ROWS + i0 + row) * 16 + r];
        ts[row][r] = s;
    }
    __syncthreads();

    int j0 = jb * 1024 + t * 4;
    f32x4 w[16];
    #pragma unroll
    for (int r = 0; r < 16; ++r)
        w[r] = *(const f32x4*)&w23[r * 4096 + j0];

    #pragma unroll 2
    for (int row = 0; row < 16; ++row) {
        const f32x4* trp = (const f32x4*)&ts[row][0];
        f32x4 t0 = trp[0], t1 = trp[1], t2 = trp[2], t3 = trp[3];
        f32x4 a = (f32x4)(0.f);
        a = fma4(t0.x, w[0],  a); a = fma4(t0.y, w[1],  a);
        a = fma4(t0.z, w[2],  a); a = fma4(t0.w, w[3],  a);
        a = fma4(t1.x, w[4],  a); a = fma4(t1.y, w[5],  a);
        a = fma4(t1.z, w[6],  a); a = fma4(t1.w, w[7],  a);
        a = fma4(t2.x, w[8],  a); a = fma4(t2.y, w[9],  a);
        a = fma4(t2.z, w[10], a); a = fma4(t2.w, w[11], a);
        a = fma4(t3.x, w[12], a); a = fma4(t3.y, w[13], a);
        a = fma4(t3.z, w[14], a); a = fma4(t3.w, w[15], a);
        __builtin_nontemporal_store(a, (f32x4*)&out[(size_t)(i0 + row) * 4096 + j0]);
    }
}

extern "C" void kernel_launch(void* const* d_in, const int* in_sizes, int n_in,
                              void* d_out, int out_size, void* d_ws, size_t ws_size,
                              hipStream_t stream) {
    const float* x  = (const float*)d_in[0];
    const float* c0 = (const float*)d_in[1];
    const float* c1 = (const float*)d_in[2];
    const float* c2 = (const float*)d_in[3];
    const float* c3 = (const float*)d_in[4];
    float* out = (float*)d_out;

    float* w01   = (float*)d_ws;
    float* w23   = w01 + 65536;
    float* tpart = w23 + 65536;

    // Prefer 16 K-segments (SEGK=256, 32 KB LDS, 5 blocks/CU); fall back
    // to 8 (SEGK=512, 64 KB LDS) if workspace is tight.
    const size_t f = sizeof(float);
    int nseg;
    if      (ws_size >= (size_t)(131072 + 16 * 131072) * f) nseg = 16;
    else if (ws_size >= (size_t)(131072 +  8 * 131072) * f) nseg = 8;
    else                                                    nseg = 4;

    tt_prep<<<512, 256, 0, stream>>>(c0, c1, c2, c3, w01, w23);
    if (nseg == 16)
        tt_xw01<256><<<dim3(256, 16), 256, 0, stream>>>(x, w01, tpart);
    else if (nseg == 8)
        tt_xw01<512><<<dim3(256, 8), 256, 0, stream>>>(x, w01, tpart);
    else
        tt_xw01<1024><<<dim3(256, 4), 256, 0, stream>>>(x, w01, tpart);
    tt_tw23<<<dim3(512, 4), 256, 0, stream>>>(tpart, w23, out, nseg);
}